// Round 9
// baseline (603.162 us; speedup 1.0000x reference)
//
#include <hip/hip_runtime.h>
#include <cstdint>
#include <cstddef>

#define DEV_INLINE __device__ __forceinline__

typedef __attribute__((ext_vector_type(8))) short bf16x8;
typedef __attribute__((ext_vector_type(16))) float f32x16;
struct __align__(8) US4 { unsigned short u[4]; };

DEV_INLINE unsigned short f2bf(float x) {
  unsigned u = __float_as_uint(x);
  return (unsigned short)((u + 0x7FFFu + ((u >> 16) & 1u)) >> 16);
}
DEV_INLINE float2 bfpair(unsigned v) {
  return make_float2(__uint_as_float(v << 16), __uint_as_float(v & 0xFFFF0000u));
}

// ---------------------------------------------------------------------------
// Batched f32 -> bf16 conversion
// ---------------------------------------------------------------------------
struct CvtSeg { const float* src; unsigned short* dst; int n; int nblk; };
struct CvtArgs { CvtSeg seg[16]; int nseg; };

__global__ __launch_bounds__(256) void convert_bf16_many(CvtArgs args) {
  int b = blockIdx.x;
  int s = 0;
  while (s < args.nseg && b >= args.seg[s].nblk) { b -= args.seg[s].nblk; ++s; }
  if (s >= args.nseg) return;
  int base = b * 1024 + threadIdx.x * 4;
  if (base >= args.seg[s].n) return;
  float4 v = *reinterpret_cast<const float4*>(args.seg[s].src + base);
  US4 o;
  o.u[0] = f2bf(v.x); o.u[1] = f2bf(v.y); o.u[2] = f2bf(v.z); o.u[3] = f2bf(v.w);
  *reinterpret_cast<US4*>(args.seg[s].dst + base) = o;
}

// ---------------------------------------------------------------------------
// bf16 MFMA GEMM bodies: C = X @ W^T + bias (f32-out and bf16-out variants)
// ---------------------------------------------------------------------------
DEV_INLINE void gemm_stage(const unsigned short* __restrict__ Xb,
                           const unsigned short* __restrict__ Wb,
                           int N, int O, int bm, int bn,
                           unsigned short* Xs, unsigned short* Ws)
{
  const int tid = threadIdx.x;
#pragma unroll
  for (int i = 0; i < 8; ++i) {
    int s = tid + 256 * i;
    int row = s >> 4, c16 = s & 15;
    uint4 v = make_uint4(0, 0, 0, 0);
    int gr = bm + row;
    if (gr < N) v = *reinterpret_cast<const uint4*>(Xb + (size_t)gr * 128 + c16 * 8);
    *reinterpret_cast<uint4*>(&Xs[(row * 16 + (c16 ^ (row & 7))) * 8]) = v;
  }
#pragma unroll
  for (int i = 0; i < 4; ++i) {
    int s = tid + 256 * i;
    int row = s >> 4, c16 = s & 15;
    uint4 v = make_uint4(0, 0, 0, 0);
    int gw = bn + row;
    if (gw < O) v = *reinterpret_cast<const uint4*>(Wb + (size_t)gw * 128 + c16 * 8);
    *reinterpret_cast<uint4*>(&Ws[(row * 16 + (c16 ^ (row & 7))) * 8]) = v;
  }
  __syncthreads();
}

DEV_INLINE void gemm_mfma(const unsigned short* Xs, const unsigned short* Ws,
                          f32x16& acc0, f32x16& acc1)
{
  const int tid = threadIdx.x;
  const int wave = tid >> 6, lane = tid & 63;
  const int l31 = lane & 31, lhi = lane >> 5;
#pragma unroll
  for (int i = 0; i < 16; ++i) { acc0[i] = 0.f; acc1[i] = 0.f; }
  const int ar = wave * 32 + l31;
#pragma unroll
  for (int ks = 0; ks < 8; ++ks) {
    int c16 = ks * 2 + lhi;
    bf16x8 a  = *reinterpret_cast<const bf16x8*>(&Xs[(ar * 16 + (c16 ^ (ar & 7))) * 8]);
    bf16x8 b0 = *reinterpret_cast<const bf16x8*>(&Ws[(l31 * 16 + (c16 ^ (l31 & 7))) * 8]);
    int br1 = 32 + l31;
    bf16x8 b1 = *reinterpret_cast<const bf16x8*>(&Ws[(br1 * 16 + (c16 ^ (br1 & 7))) * 8]);
    acc0 = __builtin_amdgcn_mfma_f32_32x32x16_bf16(a, b0, acc0, 0, 0, 0);
    acc1 = __builtin_amdgcn_mfma_f32_32x32x16_bf16(a, b1, acc1, 0, 0, 0);
  }
}

DEV_INLINE void gemm_body(
    const unsigned short* __restrict__ Xb, const unsigned short* __restrict__ Wb,
    const float* __restrict__ bias, float* __restrict__ C, int N, int O,
    int bm, int bn, unsigned short* Xs, unsigned short* Ws)
{
  gemm_stage(Xb, Wb, N, O, bm, bn, Xs, Ws);
  const int tid = threadIdx.x;
  const int wave = tid >> 6, lane = tid & 63;
  const int l31 = lane & 31, lhi = lane >> 5;
  f32x16 acc0, acc1;
  gemm_mfma(Xs, Ws, acc0, acc1);
#pragma unroll
  for (int reg = 0; reg < 16; ++reg) {
    int r = bm + wave * 32 + (reg & 3) + 8 * (reg >> 2) + 4 * lhi;
    if (r < N) {
      int c0 = bn + l31;
      if (c0 < O) C[(size_t)r * O + c0] = acc0[reg] + bias[c0];
      int c1 = bn + 32 + l31;
      if (c1 < O) C[(size_t)r * O + c1] = acc1[reg] + bias[c1];
    }
  }
}

DEV_INLINE void gemm_body_b(
    const unsigned short* __restrict__ Xb, const unsigned short* __restrict__ Wb,
    const float* __restrict__ bias, unsigned short* __restrict__ Cb, int N, int O,
    int bm, int bn, unsigned short* Xs, unsigned short* Ws)
{
  gemm_stage(Xb, Wb, N, O, bm, bn, Xs, Ws);
  const int tid = threadIdx.x;
  const int wave = tid >> 6, lane = tid & 63;
  const int l31 = lane & 31, lhi = lane >> 5;
  f32x16 acc0, acc1;
  gemm_mfma(Xs, Ws, acc0, acc1);
#pragma unroll
  for (int reg = 0; reg < 16; ++reg) {
    int r = bm + wave * 32 + (reg & 3) + 8 * (reg >> 2) + 4 * lhi;
    if (r < N) {
      int c0 = bn + l31;
      if (c0 < O) Cb[(size_t)r * O + c0] = f2bf(acc0[reg] + bias[c0]);
      int c1 = bn + 32 + l31;
      if (c1 < O) Cb[(size_t)r * O + c1] = f2bf(acc1[reg] + bias[c1]);
    }
  }
}

struct GSeg { const unsigned short* X; const unsigned short* W; const float* bias;
              float* C; int N; int O; int blk0; int xblk; };
struct GSegs { GSeg s[8]; int nseg; };

__global__ __launch_bounds__(256) void gemm_bf16_gseg(GSegs gs) {
  __shared__ __align__(16) unsigned short Xs[128 * 128];
  __shared__ __align__(16) unsigned short Ws[64 * 128];
  int bx = blockIdx.x;
  int si = 0;
  while (si + 1 < gs.nseg && bx >= gs.s[si + 1].blk0) ++si;
  const GSeg& g = gs.s[si];
  int b = bx - g.blk0;
  gemm_body(g.X, g.W, g.bias, g.C, g.N, g.O, (b % g.xblk) * 128, (b / g.xblk) * 64, Xs, Ws);
}

struct GBSeg { const unsigned short* X; const unsigned short* W; const float* bias;
               unsigned short* C; int N; int O; int blk0; int xblk; };
struct GBSegs { GBSeg s[4]; int nseg; };

__global__ __launch_bounds__(256) void gemm_bf16o_gseg(GBSegs gs) {
  __shared__ __align__(16) unsigned short Xs[128 * 128];
  __shared__ __align__(16) unsigned short Ws[64 * 128];
  int bx = blockIdx.x;
  int si = 0;
  while (si + 1 < gs.nseg && bx >= gs.s[si + 1].blk0) ++si;
  const GBSeg& g = gs.s[si];
  int b = bx - g.blk0;
  gemm_body_b(g.X, g.W, g.bias, g.C, g.N, g.O, (b % g.xblk) * 128, (b / g.xblk) * 64, Xs, Ws);
}

// ---------------------------------------------------------------------------
// Sparse row scan: block (4 waves) per row, software-pipelined loads.
// ---------------------------------------------------------------------------
DEV_INLINE void spmv_body(const float* __restrict__ A, const float* __restrict__ Xs,
                          float* __restrict__ H, unsigned short* __restrict__ Hb,
                          int row, int K, float (*red)[128])
{
  int tid = threadIdx.x, wave = tid >> 6, lane = tid & 63;
  const float4* Arow = reinterpret_cast<const float4*>(A + (size_t)row * K);
  int K4 = K >> 2;
  float acc0 = 0.f, acc1 = 0.f;
  int base = wave * 64;
  int q = base + lane;
  float4 a = (base < K4 && q < K4) ? Arow[q] : make_float4(0.f, 0.f, 0.f, 0.f);
  for (; base < K4; base += 256) {
    int nb = base + 256;
    int nq = nb + lane;
    float4 an = (nb < K4 && nq < K4) ? Arow[nq] : make_float4(0.f, 0.f, 0.f, 0.f);
#pragma unroll
    for (int c = 0; c < 4; ++c) {
      float av = (c == 0) ? a.x : (c == 1) ? a.y : (c == 2) ? a.z : a.w;
      unsigned long long mm = __ballot(av != 0.f);
      while (mm) {
        int b = __builtin_ctzll(mm);
        mm &= mm - 1;
        float v = __shfl(av, b);
        int jj = (base + b) * 4 + c;
        const float* xr = Xs + (size_t)jj * 128;
        acc0 += v * xr[lane];
        acc1 += v * xr[lane + 64];
      }
    }
    a = an;
  }
  red[wave][lane] = acc0;
  red[wave][lane + 64] = acc1;
  __syncthreads();
  if (wave == 0) {
    float r0 = red[0][lane] + red[1][lane] + red[2][lane] + red[3][lane];
    float r1 = red[0][lane + 64] + red[1][lane + 64] + red[2][lane + 64] + red[3][lane + 64];
    H[(size_t)row * 128 + lane] = r0;
    H[(size_t)row * 128 + 64 + lane] = r1;
    Hb[(size_t)row * 128 + lane] = f2bf(r0);
    Hb[(size_t)row * 128 + 64 + lane] = f2bf(r1);
  }
}

__global__ __launch_bounds__(256) void spmv_scan(
    const float* __restrict__ A, const float* __restrict__ Xs,
    float* __restrict__ H, unsigned short* __restrict__ Hb, int M, int K)
{
  __shared__ float red[4][128];
  spmv_body(A, Xs, H, Hb, blockIdx.x, K, red);
}

__global__ __launch_bounds__(256) void spmv_scan2(
    const float* __restrict__ A0, const float* __restrict__ X0,
    float* __restrict__ H0, unsigned short* __restrict__ H0b, int M0, int K0,
    const float* __restrict__ A1, const float* __restrict__ X1,
    float* __restrict__ H1, unsigned short* __restrict__ H1b, int K1)
{
  __shared__ float red[4][128];
  if ((int)blockIdx.x < M0) spmv_body(A0, X0, H0, H0b, blockIdx.x, K0, red);
  else                      spmv_body(A1, X1, H1, H1b, blockIdx.x - M0, K1, red);
}

// ---------------------------------------------------------------------------
// Fused gh-GEMM + GRU (32-row tile; reads bf16 H)
// ---------------------------------------------------------------------------
DEV_INLINE void ghgru_body(
    const unsigned short* __restrict__ Hb, const unsigned short* __restrict__ Whhb,
    const float* __restrict__ bhh, const float* __restrict__ gi,
    const float* __restrict__ hv, float* __restrict__ out,
    unsigned short* __restrict__ outb, int M, int bm, unsigned short* As)
{
  const int tid = threadIdx.x;
#pragma unroll
  for (int i = 0; i < 2; ++i) {
    int s = tid + 256 * i;
    int row = s >> 4, c16 = s & 15;
    uint4 v = make_uint4(0, 0, 0, 0);
    int gr = bm + row;
    if (gr < M) v = *reinterpret_cast<const uint4*>(Hb + (size_t)gr * 128 + c16 * 8);
    *reinterpret_cast<uint4*>(&As[(row * 16 + (c16 ^ (row & 7))) * 8]) = v;
  }
  __syncthreads();

  const int wave = tid >> 6, lane = tid & 63;
  const int l31 = lane & 31, lhi = lane >> 5;
  const int d = wave * 32 + l31;

  f32x16 ar, az, an;
#pragma unroll
  for (int i = 0; i < 16; ++i) { ar[i] = 0.f; az[i] = 0.f; an[i] = 0.f; }

#pragma unroll
  for (int ks = 0; ks < 8; ++ks) {
    int c16 = ks * 2 + lhi;
    bf16x8 a = *reinterpret_cast<const bf16x8*>(&As[(l31 * 16 + (c16 ^ (l31 & 7))) * 8]);
    const unsigned short* wb = Whhb + (size_t)c16 * 8;
    bf16x8 br = *reinterpret_cast<const bf16x8*>(wb + (size_t)d * 128);
    bf16x8 bz = *reinterpret_cast<const bf16x8*>(wb + (size_t)(128 + d) * 128);
    bf16x8 bn = *reinterpret_cast<const bf16x8*>(wb + (size_t)(256 + d) * 128);
    ar = __builtin_amdgcn_mfma_f32_32x32x16_bf16(a, br, ar, 0, 0, 0);
    az = __builtin_amdgcn_mfma_f32_32x32x16_bf16(a, bz, az, 0, 0, 0);
    an = __builtin_amdgcn_mfma_f32_32x32x16_bf16(a, bn, an, 0, 0, 0);
  }

  const float b_r = bhh[d], b_z = bhh[128 + d], b_n = bhh[256 + d];
#pragma unroll
  for (int reg = 0; reg < 16; ++reg) {
    int r = bm + (reg & 3) + 8 * (reg >> 2) + 4 * lhi;
    if (r < M) {
      const float* gir = gi + (size_t)r * 384;
      float rr = 1.f / (1.f + __expf(-(gir[d] + ar[reg] + b_r)));
      float zz = 1.f / (1.f + __expf(-(gir[128 + d] + az[reg] + b_z)));
      float nn = tanhf(gir[256 + d] + rr * (an[reg] + b_n));
      float h = hv[(size_t)r * 128 + d];
      float o = (1.f - zz) * nn + zz * h;
      out[(size_t)r * 128 + d] = o;
      outb[(size_t)r * 128 + d] = f2bf(o);
    }
  }
}

__global__ __launch_bounds__(256) void gh_gru(
    const unsigned short* __restrict__ Hb, const unsigned short* __restrict__ Whhb,
    const float* __restrict__ bhh, const float* __restrict__ gi,
    const float* __restrict__ hv, float* __restrict__ out,
    unsigned short* __restrict__ outb, int M)
{
  __shared__ __align__(16) unsigned short As[32 * 128];
  ghgru_body(Hb, Whhb, bhh, gi, hv, out, outb, M, blockIdx.x * 32, As);
}

__global__ __launch_bounds__(256) void gh_gru2(
    const unsigned short* Hb0, const unsigned short* Whh0, const float* bhh0,
    const float* gi0, const float* hv0, float* out0, unsigned short* outb0,
    int M0, int nblk0,
    const unsigned short* Hb1, const unsigned short* Whh1, const float* bhh1,
    const float* gi1, const float* hv1, float* out1, unsigned short* outb1, int M1)
{
  __shared__ __align__(16) unsigned short As[32 * 128];
  if ((int)blockIdx.x < nblk0)
    ghgru_body(Hb0, Whh0, bhh0, gi0, hv0, out0, outb0, M0, blockIdx.x * 32, As);
  else
    ghgru_body(Hb1, Whh1, bhh1, gi1, hv1, out1, outb1, M1, (blockIdx.x - nblk0) * 32, As);
}

// ---------------------------------------------------------------------------
// Wave-per-row softmax / CE / tcp. f32-logits variant (stages 0+2).
// ---------------------------------------------------------------------------
DEV_INLINE void rowops_body(int lane, const float4* __restrict__ lr,
                            const float4* __restrict__ cr,
                            const float* __restrict__ srcrow,
                            float* __restrict__ scaledrow, float* __restrict__ cep)
{
  float4 e[6];
  float m = -3.4e38f;
#pragma unroll
  for (int k = 0; k < 6; ++k) {
    int idx = k * 64 + lane;
    if (idx < 375) {
      e[k] = lr[idx];
      m = fmaxf(m, fmaxf(fmaxf(e[k].x, e[k].y), fmaxf(e[k].z, e[k].w)));
    } else {
      e[k] = make_float4(-3.4e38f, -3.4e38f, -3.4e38f, -3.4e38f);
    }
  }
#pragma unroll
  for (int o = 1; o < 64; o <<= 1) m = fmaxf(m, __shfl_xor(m, o));
  float z = 0.f;
#pragma unroll
  for (int k = 0; k < 6; ++k) {
    e[k].x = __expf(e[k].x - m); e[k].y = __expf(e[k].y - m);
    e[k].z = __expf(e[k].z - m); e[k].w = __expf(e[k].w - m);
    z += (e[k].x + e[k].y) + (e[k].z + e[k].w);
  }
#pragma unroll
  for (int o = 1; o < 64; o <<= 1) z += __shfl_xor(z, o);
  float invZ1 = 1.0f / z;
  float m2 = invZ1;
  float t = 0.f, ls = 0.f, z2 = 0.f;
#pragma unroll
  for (int k = 0; k < 6; ++k) {
    int idx = k * 64 + lane;
    if (idx < 375) {
      float4 c = cr[idx];
      float px = e[k].x * invZ1, py = e[k].y * invZ1;
      float pz = e[k].z * invZ1, pw = e[k].w * invZ1;
      t  += c.x * px + c.y * py + c.z * pz + c.w * pw;
      ls += (c.x + c.y) + (c.z + c.w);
      z2 += __expf(px - m2) + __expf(py - m2) + __expf(pz - m2) + __expf(pw - m2);
    }
  }
#pragma unroll
  for (int o = 1; o < 64; o <<= 1) {
    t += __shfl_xor(t, o); ls += __shfl_xor(ls, o); z2 += __shfl_xor(z2, o);
  }
  if (lane == 0) *cep = t - ls * (m2 + logf(z2));
  scaledrow[lane]      = t * srcrow[lane];
  scaledrow[lane + 64] = t * srcrow[lane + 64];
}

__global__ __launch_bounds__(256) void rowops2(
    const float* lgA, const float* clsA_, const float* srcA, float* scA, float* ceA, int nA,
    const float* lgB, const float* clsB_, const float* srcB, float* scB, float* ceB, int nB)
{
  int gw = (blockIdx.x * 256 + threadIdx.x) >> 6;
  if (gw >= nA + nB) return;
  int lane = threadIdx.x & 63;
  if (gw < nA) {
    rowops_body(lane,
                reinterpret_cast<const float4*>(lgA + (size_t)gw * 1500),
                reinterpret_cast<const float4*>(clsA_ + (size_t)gw * 1500),
                srcA + (size_t)gw * 128, scA + (size_t)gw * 128, ceA + gw);
  } else {
    int r = gw - nA;
    rowops_body(lane,
                reinterpret_cast<const float4*>(lgB + (size_t)r * 1500),
                reinterpret_cast<const float4*>(clsB_ + (size_t)r * 1500),
                srcB + (size_t)r * 128, scB + (size_t)r * 128, ceB + r);
  }
}

// bf16-logits variant (stages 1/3/4): logits row = 750 uints (bf16 pairs)
DEV_INLINE void rowops_body_b(int lane, const unsigned* __restrict__ lrb,
                              const float2* __restrict__ cr2,
                              const float* __restrict__ srcrow,
                              float* __restrict__ scaledrow, float* __restrict__ cep)
{
  float2 e[12];
  float m = -3.4e38f;
#pragma unroll
  for (int k = 0; k < 12; ++k) {
    int idx = k * 64 + lane;
    if (idx < 750) {
      e[k] = bfpair(lrb[idx]);
      m = fmaxf(m, fmaxf(e[k].x, e[k].y));
    } else {
      e[k] = make_float2(-3.4e38f, -3.4e38f);
    }
  }
#pragma unroll
  for (int o = 1; o < 64; o <<= 1) m = fmaxf(m, __shfl_xor(m, o));
  float z = 0.f;
#pragma unroll
  for (int k = 0; k < 12; ++k) {
    e[k].x = __expf(e[k].x - m); e[k].y = __expf(e[k].y - m);
    z += e[k].x + e[k].y;
  }
#pragma unroll
  for (int o = 1; o < 64; o <<= 1) z += __shfl_xor(z, o);
  float invZ1 = 1.0f / z;
  float m2 = invZ1;
  float t = 0.f, ls = 0.f, z2 = 0.f;
#pragma unroll
  for (int k = 0; k < 12; ++k) {
    int idx = k * 64 + lane;
    if (idx < 750) {
      float2 c = cr2[idx];
      float px = e[k].x * invZ1, py = e[k].y * invZ1;
      t  += c.x * px + c.y * py;
      ls += c.x + c.y;
      z2 += __expf(px - m2) + __expf(py - m2);
    }
  }
#pragma unroll
  for (int o = 1; o < 64; o <<= 1) {
    t += __shfl_xor(t, o); ls += __shfl_xor(ls, o); z2 += __shfl_xor(z2, o);
  }
  if (lane == 0) *cep = t - ls * (m2 + logf(z2));
  scaledrow[lane]      = t * srcrow[lane];
  scaledrow[lane + 64] = t * srcrow[lane + 64];
}

__global__ __launch_bounds__(256) void rowops2b(
    const unsigned* lgA, const float* clsA_, const float* srcA, float* scA, float* ceA, int nA,
    const unsigned* lgB, const float* clsB_, const float* srcB, float* scB, float* ceB, int nB)
{
  int gw = (blockIdx.x * 256 + threadIdx.x) >> 6;
  if (gw >= nA + nB) return;
  int lane = threadIdx.x & 63;
  if (gw < nA) {
    rowops_body_b(lane, lgA + (size_t)gw * 750,
                  reinterpret_cast<const float2*>(clsA_ + (size_t)gw * 1500),
                  srcA + (size_t)gw * 128, scA + (size_t)gw * 128, ceA + gw);
  } else {
    int r = gw - nA;
    rowops_body_b(lane, lgB + (size_t)r * 750,
                  reinterpret_cast<const float2*>(clsB_ + (size_t)r * 1500),
                  srcB + (size_t)r * 128, scB + (size_t)r * 128, ceB + r);
  }
}

__global__ __launch_bounds__(256) void rowops1b(
    const unsigned* lg, const float* cls, const float* src, float* sc, float* ce, int n)
{
  int gw = (blockIdx.x * 256 + threadIdx.x) >> 6;
  if (gw >= n) return;
  int lane = threadIdx.x & 63;
  rowops_body_b(lane, lg + (size_t)gw * 750,
                reinterpret_cast<const float2*>(cls + (size_t)gw * 1500),
                src + (size_t)gw * 128, sc + (size_t)gw * 128, ce + gw);
}

// ---------------------------------------------------------------------------
// Fuse pipeline
// ---------------------------------------------------------------------------
__global__ __launch_bounds__(256) void fuse_scores_all(
    const float* __restrict__ e0, const float* __restrict__ e1,
    const float* __restrict__ W2, const float* __restrict__ b2,
    const float* __restrict__ W3, const float* __restrict__ b3,
    float* __restrict__ s0, float* __restrict__ s1)
{
  int lane = threadIdx.x & 63;
  int row = (blockIdx.x * 256 + threadIdx.x) >> 6;
  if (row >= 18500) return;
  float a0 = e0[(size_t)row * 128 + lane] * W2[lane] + e0[(size_t)row * 128 + 64 + lane] * W2[64 + lane];
  float a1 = e1[(size_t)row * 128 + lane] * W3[lane] + e1[(size_t)row * 128 + 64 + lane] * W3[64 + lane];
#pragma unroll
  for (int o = 32; o > 0; o >>= 1) { a0 += __shfl_down(a0, o); a1 += __shfl_down(a1, o); }
  if (lane == 0) {
    s0[row] = fmaxf(a0 + b2[0], 0.f);
    s1[row] = fmaxf(a1 + b3[0], 0.f);
  }
}

__global__ __launch_bounds__(1024) void denom4(
    const float* __restrict__ s0, const float* __restrict__ s1,
    float* __restrict__ den)
{
  __shared__ float red[1024];
  const int ns[4]   = {8000, 3000, 1500, 6000};
  const int offs[4] = {0, 8000, 11000, 12500};
  int b = blockIdx.x;
  int n = ns[b];
  const float* p0 = s0 + offs[b];
  const float* p1 = s1 + offs[b];
  int tid = threadIdx.x;
  float m = -3.4e38f;
  for (int i = tid; i < n; i += 1024) m = fmaxf(m, p0[i]);
  red[tid] = m; __syncthreads();
  for (int s = 512; s > 0; s >>= 1) { if (tid < s) red[tid] = fmaxf(red[tid], red[tid + s]); __syncthreads(); }
  float m0 = red[0]; __syncthreads();
  float z = 0.f;
  for (int i = tid; i < n; i += 1024) z += __expf(p0[i] - m0);
  red[tid] = z; __syncthreads();
  for (int s = 512; s > 0; s >>= 1) { if (tid < s) red[tid] += red[tid + s]; __syncthreads(); }
  float Z0 = red[0]; __syncthreads();
  m = -3.4e38f;
  for (int i = tid; i < n; i += 1024) m = fmaxf(m, p1[i]);
  red[tid] = m; __syncthreads();
  for (int s = 512; s > 0; s >>= 1) { if (tid < s) red[tid] = fmaxf(red[tid], red[tid + s]); __syncthreads(); }
  float m1 = red[0]; __syncthreads();
  z = 0.f;
  for (int i = tid; i < n; i += 1024) z += __expf(p1[i] - m1);
  red[tid] = z; __syncthreads();
  for (int s = 512; s > 0; s >>= 1) { if (tid < s) red[tid] += red[tid + s]; __syncthreads(); }
  if (tid == 0) { den[b * 4] = m0; den[b * 4 + 1] = Z0; den[b * 4 + 2] = m1; den[b * 4 + 3] = red[0]; }
}

__global__ __launch_bounds__(256) void fuse_emb_all(
    const float* __restrict__ e0, const float* __restrict__ e1,
    const float* __restrict__ s0, const float* __restrict__ s1,
    const float* __restrict__ den, const float* __restrict__ rel,
    float* __restrict__ fe, unsigned short* __restrict__ feb,
    float* __restrict__ rel_out, unsigned* __restrict__ ctr)
{
  int t = blockIdx.x * 256 + threadIdx.x;
  if (t == 0) *ctr = 0;   // reset edge-kernel completion counter for this call
  const int tot2 = 18500 * 64;
  if (t < tot2) {
    int idx = t * 2;
    int row = idx >> 7;
    int e = (row < 8000) ? 0 : (row < 11000) ? 1 : (row < 12500) ? 2 : 3;
    float a0 = __expf(s0[row] - den[e * 4]) / den[e * 4 + 1];
    float a1 = __expf(s1[row] - den[e * 4 + 2]) / den[e * 4 + 3];
    float2 v0 = *reinterpret_cast<const float2*>(e0 + idx);
    float2 v1 = *reinterpret_cast<const float2*>(e1 + idx);
    float r0 = fmaxf(a0 * v0.x + a1 * v1.x, 0.f);
    float r1 = fmaxf(a0 * v0.y + a1 * v1.y, 0.f);
    *reinterpret_cast<float2*>(fe + idx) = make_float2(r0, r1);
    unsigned pb = (unsigned)f2bf(r0) | ((unsigned)f2bf(r1) << 16);
    *reinterpret_cast<unsigned*>(feb + idx) = pb;
  } else if (t < tot2 + 768) {
    int k = (t - tot2) * 2;
    *reinterpret_cast<float2*>(rel_out + k) = *reinterpret_cast<const float2*>(rel + k);
  }
}

// ---------------------------------------------------------------------------
// Edge losses (bf16 gathers) + last-block final reduce
// ---------------------------------------------------------------------------
__global__ __launch_bounds__(256) void edge_both_final(
    const int* __restrict__ ud, const int* __restrict__ us,
    const unsigned short* __restrict__ feb, const unsigned short* __restrict__ relb,
    float* __restrict__ partial, int En,
    const float* __restrict__ cebuf, unsigned* __restrict__ ctr,
    float* __restrict__ out)
{
  int lane = threadIdx.x & 63;
  int wid = threadIdx.x >> 6;
  bool is_d = (blockIdx.x < 1024);
  int bb = is_d ? blockIdx.x : blockIdx.x - 1024;
  int gw = bb * 4 + wid;
  const int nw = 1024 * 4;
  float acc = 0.f;
  if (is_d) {
    for (int e = gw; e < En; e += nw) {
      int4 ei = *reinterpret_cast<const int4*>(ud + (size_t)e * 4);
      float2 fi = bfpair(reinterpret_cast<const unsigned*>(feb + (size_t)ei.x * 128)[lane]);
      float2 fj = bfpair(reinterpret_cast<const unsigned*>(feb + (size_t)ei.y * 128)[lane]);
      float2 rr = bfpair(reinterpret_cast<const unsigned*>(relb + (size_t)ei.w * 128)[lane]);
      float d = rr.x * tanhf(fi.x + fj.x) + rr.y * tanhf(fi.y + fj.y);
#pragma unroll
      for (int o = 32; o > 0; o >>= 1) d += __shfl_down(d, o);
      if (lane == 0) {
        float x = (float)ei.z * d;
        acc += (x >= 0.f) ? log1pf(__expf(-x)) : (-x + log1pf(__expf(x)));
      }
    }
  } else {
    for (int e = gw; e < En; e += nw) {
      int i = us[(size_t)e * 3], j = us[(size_t)e * 3 + 1], lab = us[(size_t)e * 3 + 2];
      float2 fi = bfpair(reinterpret_cast<const unsigned*>(feb + (size_t)i * 128)[lane]);
      float2 fj = bfpair(reinterpret_cast<const unsigned*>(feb + (size_t)j * 128)[lane]);
      float d = fi.x * fj.x + fi.y * fj.y;
#pragma unroll
      for (int o = 32; o > 0; o >>= 1) d += __shfl_down(d, o);
      if (lane == 0) {
        float x = (float)lab * d;
        acc += (x >= 0.f) ? log1pf(__expf(-x)) : (-x + log1pf(__expf(x)));
      }
    }
  }
  __shared__ float red[4];
  if (lane == 0) red[wid] = acc;
  __syncthreads();
  __shared__ unsigned myturn;
  if (threadIdx.x == 0) {
    partial[blockIdx.x] = red[0] + red[1] + red[2] + red[3];
    __threadfence();
    myturn = atomicAdd(ctr, 1u);
  }
  __syncthreads();
  if (myturn == 2047) {
    // last block: global reduce of edge partials + ce means
    __threadfence();
    __shared__ float red2[256];
    int tid = threadIdx.x;
    float a = 0.f;
    for (int i = tid; i < 2048; i += 256) a += partial[i];
    red2[tid] = a; __syncthreads();
    for (int s = 128; s > 0; s >>= 1) { if (tid < s) red2[tid] += red2[tid + s]; __syncthreads(); }
    float total = red2[0]; __syncthreads();
    const int ns[5] = {3000, 8000, 6000, 8000, 3000};
#pragma unroll
    for (int seg = 0; seg < 5; ++seg) {
      const float* v = cebuf + seg * 8000;
      float s = 0.f;
      for (int i = tid; i < ns[seg]; i += 256) s += v[i];
      red2[tid] = s; __syncthreads();
      for (int st = 128; st > 0; st >>= 1) { if (tid < st) red2[tid] += red2[tid + st]; __syncthreads(); }
      if (tid == 0) total -= red2[0] / (float)ns[seg];
      __syncthreads();
    }
    if (tid == 0) out[0] = total;
  }
}

// ---------------------------------------------------------------------------
extern "C" void kernel_launch(void* const* d_in, const int* in_sizes, int n_in,
                              void* d_out, int out_size, void* d_ws, size_t ws_size,
                              hipStream_t stream)
{
  const float* feat_P = (const float*)d_in[0];
  const float* feat_V = (const float*)d_in[1];
  const float* feat_C = (const float*)d_in[2];
  const float* feat_A = (const float*)d_in[3];
  const float* W1 = (const float*)d_in[4];
  const float* b1 = (const float*)d_in[5];
  const float* W2 = (const float*)d_in[6];
  const float* b2 = (const float*)d_in[7];
  const float* W3 = (const float*)d_in[8];
  const float* b3 = (const float*)d_in[9];
  const float* L00W = (const float*)d_in[10];
  const float* L00b = (const float*)d_in[11];
  const float* L01W = (const float*)d_in[12];
  const float* L01b = (const float*)d_in[13];
  const float* L10W = (const float*)d_in[14];
  const float* L10b = (const float*)d_in[15];
  const float* L11W = (const float*)d_in[16];
  const float* L11b = (const float*)d_in[17];
  const float* L12W = (const float*)d_in[18];
  const float* L12b = (const float*)d_in[19];
  const float* g0_Wih = (const float*)d_in[20];
  const float* g0_Whh = (const float*)d_in[21];
  const float* g0_bih = (const float*)d_in[22];
  const float* g0_bhh = (const float*)d_in[23];
  const float* g1_Wih = (const float*)d_in[24];
  const float* g1_Whh = (const float*)d_in[25];
  const float* g1_bih = (const float*)d_in[26];
  const float* g1_bhh = (const float*)d_in[27];
  const float* rel_emb = (const float*)d_in[28];
  const float* adj00 = (const float*)d_in[29];
  const float* adj01 = (const float*)d_in[30];
  const float* adj10 = (const float*)d_in[31];
  const float* adj11 = (const float*)d_in[32];
  const float* adj12 = (const float*)d_in[33];
  const float* clsA = (const float*)d_in[34];
  const float* clsP = (const float*)d_in[35];
  const float* clsV = (const float*)d_in[36];
  const int* u_s = (const int*)d_in[37];
  const int* u_d = (const int*)d_in[38];

  float* out = (float*)d_out;
  float* fe = out + 1;
  float* rel_out = out + 1 + 18500 * 128;

  float* ws = (float*)d_ws;
  size_t o = 0;
  auto alloc = [&](size_t n) { float* p = ws + o; o += n; return p; };
  float* selfb   = alloc((size_t)18500 * 128);
  float* stcat   = alloc((size_t)18500 * 128);   // P0|V1|C1|A0
  float* stP1    = alloc((size_t)8000 * 128);
  float* gi      = alloc((size_t)26500 * 384);
  float* logits0 = alloc((size_t)3000 * 1500);   // stage 0 (f32)
  float* logits2 = alloc((size_t)6000 * 1500);   // stage 2 (f32)
  float* scaled0 = alloc((size_t)3000 * 128);
  float* scaled1 = alloc((size_t)8000 * 128);
  float* scaled2 = alloc((size_t)6000 * 128);
  float* scaled3 = alloc((size_t)8000 * 128);
  float* scaled4 = alloc((size_t)3000 * 128);
  float* h0      = alloc((size_t)8000 * 128);
  float* h2      = alloc((size_t)8000 * 128);
  float* h1      = alloc((size_t)6000 * 128);
  float* h3      = alloc((size_t)3000 * 128);
  float* h4      = alloc((size_t)1500 * 128);
  float* cebuf   = alloc(5 * 8000);
  float* s0b = alloc(18500);
  float* s1b = alloc(18500);
  float* den = alloc(16);
  float* partial = alloc(2048);
  unsigned* ctr = (unsigned*)alloc(4);
  auto allocb = [&](size_t nelem) { unsigned short* p = (unsigned short*)(ws + o); o += (nelem + 1) / 2; return p; };
  unsigned short* featb  = allocb((size_t)18500 * 128);
  unsigned short* stcatb = allocb((size_t)18500 * 128);
  unsigned short* stP1b  = allocb((size_t)8000 * 128);
  unsigned short* feb    = allocb((size_t)18500 * 128);
  unsigned short* h0b    = allocb((size_t)8000 * 128);
  unsigned short* h2b    = allocb((size_t)8000 * 128);
  unsigned short* h1b    = allocb((size_t)6000 * 128);
  unsigned short* h3b    = allocb((size_t)3000 * 128);
  unsigned short* h4b    = allocb((size_t)1500 * 128);
  unsigned short* lg1b   = allocb((size_t)8000 * 1500);  // bf16 logits stage 1 (and 4)
  unsigned short* lg3b   = allocb((size_t)8000 * 1500);  // bf16 logits stage 3
  unsigned short* relb   = allocb(12 * 128);
  unsigned short* W1b = allocb(128 * 128);
  unsigned short* L00Wb = allocb(1500 * 128);
  unsigned short* L01Wb = allocb(1500 * 128);
  unsigned short* L10Wb = allocb(1500 * 128);
  unsigned short* L11Wb = allocb(1500 * 128);
  unsigned short* L12Wb = allocb(1500 * 128);
  unsigned short* g0Wihb = allocb(384 * 128);
  unsigned short* g0Whhb = allocb(384 * 128);
  unsigned short* g1Wihb = allocb(384 * 128);
  unsigned short* g1Whhb = allocb(384 * 128);
  unsigned short* featPb = featb;
  unsigned short* featVb = featb + (size_t)8000 * 128;
  unsigned short* featCb = featb + (size_t)11000 * 128;
  unsigned short* featAb = featb + (size_t)12500 * 128;
  float* stP0 = stcat;
  float* stV1 = stcat + (size_t)8000 * 128;
  float* stC1 = stcat + (size_t)11000 * 128;
  float* stA0 = stcat + (size_t)12500 * 128;
  unsigned short* stP0b = stcatb;
  unsigned short* stV1b = stcatb + (size_t)8000 * 128;
  unsigned short* stC1b = stcatb + (size_t)11000 * 128;
  unsigned short* stA0b = stcatb + (size_t)12500 * 128;
  (void)ws_size; (void)in_sizes; (void)n_in; (void)out_size;

  dim3 blk(256);

  // --- 1. batched f32->bf16 conversion ---
  CvtArgs ca{};
  int nseg = 0, totblk = 0;
  auto addseg = [&](const float* src, unsigned short* dst, int n) {
    ca.seg[nseg].src = src; ca.seg[nseg].dst = dst; ca.seg[nseg].n = n;
    ca.seg[nseg].nblk = (n + 1023) / 1024; totblk += ca.seg[nseg].nblk; ++nseg;
  };
  addseg(feat_P, featPb, 8000 * 128);
  addseg(feat_V, featVb, 3000 * 128);
  addseg(feat_C, featCb, 1500 * 128);
  addseg(feat_A, featAb, 6000 * 128);
  addseg(W1, W1b, 128 * 128);
  addseg(L00W, L00Wb, 1500 * 128);
  addseg(L01W, L01Wb, 1500 * 128);
  addseg(L10W, L10Wb, 1500 * 128);
  addseg(L11W, L11Wb, 1500 * 128);
  addseg(L12W, L12Wb, 1500 * 128);
  addseg(g0_Wih, g0Wihb, 384 * 128);
  addseg(g0_Whh, g0Whhb, 384 * 128);
  addseg(g1_Wih, g1Wihb, 384 * 128);
  addseg(g1_Whh, g1Whhb, 384 * 128);
  addseg(rel_emb, relb, 12 * 128);
  ca.nseg = nseg;
  hipLaunchKernelGGL(convert_bf16_many, dim3(totblk), blk, 0, stream, ca);

  const size_t giOff[5] = {0, 8000, 14000, 22000, 25000};

  // --- 2. static GEMMs (self + 5 gi + f32 logits for stages 0,2) ---
  {
    GSegs gs{};
    int nb = 0, k = 0;
    auto add = [&](const unsigned short* X, const unsigned short* W, const float* bias,
                   float* C, int N, int O) {
      int xb = (N + 127) / 128, yb = (O + 63) / 64;
      gs.s[k] = GSeg{X, W, bias, C, N, O, nb, xb};
      nb += xb * yb; ++k;
    };
    add(featb,  W1b,    b1,     selfb,               18500, 128);
    add(featPb, g0Wihb, g0_bih, gi + giOff[0] * 384, 8000, 384);
    add(featAb, g0Wihb, g0_bih, gi + giOff[1] * 384, 6000, 384);
    add(featPb, g1Wihb, g1_bih, gi + giOff[2] * 384, 8000, 384);
    add(featVb, g1Wihb, g1_bih, gi + giOff[3] * 384, 3000, 384);
    add(featCb, g1Wihb, g1_bih, gi + giOff[4] * 384, 1500, 384);
    add(featVb, L00Wb,  L00b,   logits0,             3000, 1500);
    add(featAb, L10Wb,  L10b,   logits2,             6000, 1500);
    gs.nseg = k;
    hipLaunchKernelGGL(gemm_bf16_gseg, dim3(nb), blk, 0, stream, gs);
  }

  // --- 3. rowops stages 0+2 (f32 logits) ---
  hipLaunchKernelGGL(rowops2, dim3((9000 * 64 + 255) / 256), blk, 0, stream,
                     logits0, clsV, feat_V, scaled0, cebuf + 0 * 8000, 3000,
                     logits2, clsA, feat_A, scaled2, cebuf + 2 * 8000, 6000);
  // --- 4. spmv stages 0+2 ---
  hipLaunchKernelGGL(spmv_scan2, dim3(16000), blk, 0, stream,
                     adj00, scaled0, h0, h0b, 8000, 3000,
                     adj10, scaled2, h2, h2b, 6000);
  // --- 5. gh_gru stages 0+2 -> stP0, stP1 ---
  hipLaunchKernelGGL(gh_gru2, dim3(500), blk, 0, stream,
                     h0b, g0Whhb, g0_bhh, gi + giOff[0] * 384, h0, stP0, stP0b, 8000, 250,
                     h2b, g1Whhb, g1_bhh, gi + giOff[2] * 384, h2, stP1, stP1b, 8000);
  // --- 6. logits stages 1+3 (bf16 out) ---
  {
    GBSegs gs{};
    gs.s[0] = GBSeg{stP0b, L01Wb, L01b, lg1b, 8000, 1500, 0,    63};
    gs.s[1] = GBSeg{stP1b, L11Wb, L11b, lg3b, 8000, 1500, 1512, 63};
    gs.nseg = 2;
    hipLaunchKernelGGL(gemm_bf16o_gseg, dim3(3024), blk, 0, stream, gs);
  }
  // --- 7. rowops stages 1+3 (bf16 logits) ---
  hipLaunchKernelGGL(rowops2b, dim3((16000 * 64 + 255) / 256), blk, 0, stream,
                     (const unsigned*)lg1b, clsP, stP0, scaled1, cebuf + 1 * 8000, 8000,
                     (const unsigned*)lg3b, clsP, stP1, scaled3, cebuf + 3 * 8000, 8000);
  // --- 8. spmv stages 1+3 ---
  hipLaunchKernelGGL(spmv_scan2, dim3(9000), blk, 0, stream,
                     adj01, scaled1, h1, h1b, 6000, 8000,
                     adj11, scaled3, h3, h3b, 8000);
  // --- 9. gh_gru stages 1+3 -> stA0, stV1 ---
  hipLaunchKernelGGL(gh_gru2, dim3(188 + 94), blk, 0, stream,
                     h1b, g0Whhb, g0_bhh, gi + giOff[1] * 384, h1, stA0, stA0b, 6000, 188,
                     h3b, g1Whhb, g1_bhh, gi + giOff[3] * 384, h3, stV1, stV1b, 3000);
  // --- 10-13. stage 4 ---
  {
    GBSegs gs{};
    gs.s[0] = GBSeg{stV1b, L12Wb, L12b, lg1b, 3000, 1500, 0, 24};
    gs.nseg = 1;
    hipLaunchKernelGGL(gemm_bf16o_gseg, dim3(24 * 24), blk, 0, stream, gs);
  }
  hipLaunchKernelGGL(rowops1b, dim3((3000 * 64 + 255) / 256), blk, 0, stream,
                     (const unsigned*)lg1b, clsV, stV1, scaled4, cebuf + 4 * 8000, 3000);
  hipLaunchKernelGGL(spmv_scan, dim3(1500), blk, 0, stream, adj12, scaled4, h4, h4b, 1500, 3000);
  hipLaunchKernelGGL(gh_gru, dim3(47), blk, 0, stream,
                     h4b, g1Whhb, g1_bhh, gi + giOff[4] * 384, h4, stC1, stC1b, 1500);

  // --- 14-16. fuse pipeline ---
  hipLaunchKernelGGL(fuse_scores_all, dim3((18500 + 3) / 4), blk, 0, stream,
                     selfb, stcat, W2, b2, W3, b3, s0b, s1b);
  hipLaunchKernelGGL(denom4, dim3(4), dim3(1024), 0, stream, s0b, s1b, den);
  hipLaunchKernelGGL(fuse_emb_all, dim3((18500 * 64 + 768 + 255) / 256), blk, 0, stream,
                     selfb, stcat, s0b, s1b, den, rel_emb, fe, feb, rel_out, ctr);

  // --- 17. edges + final (last-block reduce) ---
  hipLaunchKernelGGL(edge_both_final, dim3(2048), blk, 0, stream,
                     u_d, u_s, feb, relb, partial, 150000, cebuf, ctr, out);
}

// Round 10
// 515.978 us; speedup vs baseline: 1.1690x; 1.1690x over previous
//
#include <hip/hip_runtime.h>
#include <cstdint>
#include <cstddef>

#define DEV_INLINE __device__ __forceinline__

typedef __attribute__((ext_vector_type(8))) short bf16x8;
typedef __attribute__((ext_vector_type(16))) float f32x16;
struct __align__(8) US4 { unsigned short u[4]; };

DEV_INLINE unsigned short f2bf(float x) {
  unsigned u = __float_as_uint(x);
  return (unsigned short)((u + 0x7FFFu + ((u >> 16) & 1u)) >> 16);
}
DEV_INLINE float2 bfpair(unsigned v) {
  return make_float2(__uint_as_float(v << 16), __uint_as_float(v & 0xFFFF0000u));
}
DEV_INLINE float ftanh(float x) {          // exact at saturation; ~1e-7 rel err
  float e = __expf(2.0f * x);
  return 1.0f - 2.0f / (e + 1.0f);
}
DEV_INLINE float softplus_neg(float x) {   // log(1+exp(-x)), stable
  return (x >= 0.f) ? log1pf(__expf(-x)) : (-x + log1pf(__expf(x)));
}

// ---------------------------------------------------------------------------
// Batched f32 -> bf16 conversion
// ---------------------------------------------------------------------------
struct CvtSeg { const float* src; unsigned short* dst; int n; int nblk; };
struct CvtArgs { CvtSeg seg[16]; int nseg; };

__global__ __launch_bounds__(256) void convert_bf16_many(CvtArgs args) {
  int b = blockIdx.x;
  int s = 0;
  while (s < args.nseg && b >= args.seg[s].nblk) { b -= args.seg[s].nblk; ++s; }
  if (s >= args.nseg) return;
  int base = b * 1024 + threadIdx.x * 4;
  if (base >= args.seg[s].n) return;
  float4 v = *reinterpret_cast<const float4*>(args.seg[s].src + base);
  US4 o;
  o.u[0] = f2bf(v.x); o.u[1] = f2bf(v.y); o.u[2] = f2bf(v.z); o.u[3] = f2bf(v.w);
  *reinterpret_cast<US4*>(args.seg[s].dst + base) = o;
}

// ---------------------------------------------------------------------------
// bf16 MFMA GEMM bodies: C = X @ W^T + bias (f32-out and bf16-out variants)
// ---------------------------------------------------------------------------
DEV_INLINE void gemm_stage(const unsigned short* __restrict__ Xb,
                           const unsigned short* __restrict__ Wb,
                           int N, int O, int bm, int bn,
                           unsigned short* Xs, unsigned short* Ws)
{
  const int tid = threadIdx.x;
#pragma unroll
  for (int i = 0; i < 8; ++i) {
    int s = tid + 256 * i;
    int row = s >> 4, c16 = s & 15;
    uint4 v = make_uint4(0, 0, 0, 0);
    int gr = bm + row;
    if (gr < N) v = *reinterpret_cast<const uint4*>(Xb + (size_t)gr * 128 + c16 * 8);
    *reinterpret_cast<uint4*>(&Xs[(row * 16 + (c16 ^ (row & 7))) * 8]) = v;
  }
#pragma unroll
  for (int i = 0; i < 4; ++i) {
    int s = tid + 256 * i;
    int row = s >> 4, c16 = s & 15;
    uint4 v = make_uint4(0, 0, 0, 0);
    int gw = bn + row;
    if (gw < O) v = *reinterpret_cast<const uint4*>(Wb + (size_t)gw * 128 + c16 * 8);
    *reinterpret_cast<uint4*>(&Ws[(row * 16 + (c16 ^ (row & 7))) * 8]) = v;
  }
  __syncthreads();
}

DEV_INLINE void gemm_mfma(const unsigned short* Xs, const unsigned short* Ws,
                          f32x16& acc0, f32x16& acc1)
{
  const int tid = threadIdx.x;
  const int wave = tid >> 6, lane = tid & 63;
  const int l31 = lane & 31, lhi = lane >> 5;
#pragma unroll
  for (int i = 0; i < 16; ++i) { acc0[i] = 0.f; acc1[i] = 0.f; }
  const int ar = wave * 32 + l31;
#pragma unroll
  for (int ks = 0; ks < 8; ++ks) {
    int c16 = ks * 2 + lhi;
    bf16x8 a  = *reinterpret_cast<const bf16x8*>(&Xs[(ar * 16 + (c16 ^ (ar & 7))) * 8]);
    bf16x8 b0 = *reinterpret_cast<const bf16x8*>(&Ws[(l31 * 16 + (c16 ^ (l31 & 7))) * 8]);
    int br1 = 32 + l31;
    bf16x8 b1 = *reinterpret_cast<const bf16x8*>(&Ws[(br1 * 16 + (c16 ^ (br1 & 7))) * 8]);
    acc0 = __builtin_amdgcn_mfma_f32_32x32x16_bf16(a, b0, acc0, 0, 0, 0);
    acc1 = __builtin_amdgcn_mfma_f32_32x32x16_bf16(a, b1, acc1, 0, 0, 0);
  }
}

DEV_INLINE void gemm_body(
    const unsigned short* __restrict__ Xb, const unsigned short* __restrict__ Wb,
    const float* __restrict__ bias, float* __restrict__ C, int N, int O,
    int bm, int bn, unsigned short* Xs, unsigned short* Ws)
{
  gemm_stage(Xb, Wb, N, O, bm, bn, Xs, Ws);
  const int tid = threadIdx.x;
  const int wave = tid >> 6, lane = tid & 63;
  const int l31 = lane & 31, lhi = lane >> 5;
  f32x16 acc0, acc1;
  gemm_mfma(Xs, Ws, acc0, acc1);
#pragma unroll
  for (int reg = 0; reg < 16; ++reg) {
    int r = bm + wave * 32 + (reg & 3) + 8 * (reg >> 2) + 4 * lhi;
    if (r < N) {
      int c0 = bn + l31;
      if (c0 < O) C[(size_t)r * O + c0] = acc0[reg] + bias[c0];
      int c1 = bn + 32 + l31;
      if (c1 < O) C[(size_t)r * O + c1] = acc1[reg] + bias[c1];
    }
  }
}

DEV_INLINE void gemm_body_b(
    const unsigned short* __restrict__ Xb, const unsigned short* __restrict__ Wb,
    const float* __restrict__ bias, unsigned short* __restrict__ Cb, int N, int O,
    int bm, int bn, unsigned short* Xs, unsigned short* Ws)
{
  gemm_stage(Xb, Wb, N, O, bm, bn, Xs, Ws);
  const int tid = threadIdx.x;
  const int wave = tid >> 6, lane = tid & 63;
  const int l31 = lane & 31, lhi = lane >> 5;
  f32x16 acc0, acc1;
  gemm_mfma(Xs, Ws, acc0, acc1);
#pragma unroll
  for (int reg = 0; reg < 16; ++reg) {
    int r = bm + wave * 32 + (reg & 3) + 8 * (reg >> 2) + 4 * lhi;
    if (r < N) {
      int c0 = bn + l31;
      if (c0 < O) Cb[(size_t)r * O + c0] = f2bf(acc0[reg] + bias[c0]);
      int c1 = bn + 32 + l31;
      if (c1 < O) Cb[(size_t)r * O + c1] = f2bf(acc1[reg] + bias[c1]);
    }
  }
}

struct GSeg { const unsigned short* X; const unsigned short* W; const float* bias;
              float* C; int N; int O; int blk0; int xblk; };
struct GSegs { GSeg s[8]; int nseg; };

__global__ __launch_bounds__(256) void gemm_bf16_gseg(GSegs gs) {
  __shared__ __align__(16) unsigned short Xs[128 * 128];
  __shared__ __align__(16) unsigned short Ws[64 * 128];
  int bx = blockIdx.x;
  int si = 0;
  while (si + 1 < gs.nseg && bx >= gs.s[si + 1].blk0) ++si;
  const GSeg& g = gs.s[si];
  int b = bx - g.blk0;
  gemm_body(g.X, g.W, g.bias, g.C, g.N, g.O, (b % g.xblk) * 128, (b / g.xblk) * 64, Xs, Ws);
}

struct GBSeg { const unsigned short* X; const unsigned short* W; const float* bias;
               unsigned short* C; int N; int O; int blk0; int xblk; };
struct GBSegs { GBSeg s[4]; int nseg; };

__global__ __launch_bounds__(256) void gemm_bf16o_gseg(GBSegs gs) {
  __shared__ __align__(16) unsigned short Xs[128 * 128];
  __shared__ __align__(16) unsigned short Ws[64 * 128];
  int bx = blockIdx.x;
  int si = 0;
  while (si + 1 < gs.nseg && bx >= gs.s[si + 1].blk0) ++si;
  const GBSeg& g = gs.s[si];
  int b = bx - g.blk0;
  gemm_body_b(g.X, g.W, g.bias, g.C, g.N, g.O, (b % g.xblk) * 128, (b / g.xblk) * 64, Xs, Ws);
}

// ---------------------------------------------------------------------------
// Sparse row scan: block (4 waves) per row, software-pipelined loads.
// ---------------------------------------------------------------------------
DEV_INLINE void spmv_body(const float* __restrict__ A, const float* __restrict__ Xs,
                          float* __restrict__ H, unsigned short* __restrict__ Hb,
                          int row, int K, float (*red)[128])
{
  int tid = threadIdx.x, wave = tid >> 6, lane = tid & 63;
  const float4* Arow = reinterpret_cast<const float4*>(A + (size_t)row * K);
  int K4 = K >> 2;
  float acc0 = 0.f, acc1 = 0.f;
  int base = wave * 64;
  int q = base + lane;
  float4 a = (base < K4 && q < K4) ? Arow[q] : make_float4(0.f, 0.f, 0.f, 0.f);
  for (; base < K4; base += 256) {
    int nb = base + 256;
    int nq = nb + lane;
    float4 an = (nb < K4 && nq < K4) ? Arow[nq] : make_float4(0.f, 0.f, 0.f, 0.f);
#pragma unroll
    for (int c = 0; c < 4; ++c) {
      float av = (c == 0) ? a.x : (c == 1) ? a.y : (c == 2) ? a.z : a.w;
      unsigned long long mm = __ballot(av != 0.f);
      while (mm) {
        int b = __builtin_ctzll(mm);
        mm &= mm - 1;
        float v = __shfl(av, b);
        int jj = (base + b) * 4 + c;
        const float* xr = Xs + (size_t)jj * 128;
        acc0 += v * xr[lane];
        acc1 += v * xr[lane + 64];
      }
    }
    a = an;
  }
  red[wave][lane] = acc0;
  red[wave][lane + 64] = acc1;
  __syncthreads();
  if (wave == 0) {
    float r0 = red[0][lane] + red[1][lane] + red[2][lane] + red[3][lane];
    float r1 = red[0][lane + 64] + red[1][lane + 64] + red[2][lane + 64] + red[3][lane + 64];
    H[(size_t)row * 128 + lane] = r0;
    H[(size_t)row * 128 + 64 + lane] = r1;
    Hb[(size_t)row * 128 + lane] = f2bf(r0);
    Hb[(size_t)row * 128 + 64 + lane] = f2bf(r1);
  }
}

__global__ __launch_bounds__(256) void spmv_scan(
    const float* __restrict__ A, const float* __restrict__ Xs,
    float* __restrict__ H, unsigned short* __restrict__ Hb, int M, int K)
{
  __shared__ float red[4][128];
  spmv_body(A, Xs, H, Hb, blockIdx.x, K, red);
}

__global__ __launch_bounds__(256) void spmv_scan2(
    const float* __restrict__ A0, const float* __restrict__ X0,
    float* __restrict__ H0, unsigned short* __restrict__ H0b, int M0, int K0,
    const float* __restrict__ A1, const float* __restrict__ X1,
    float* __restrict__ H1, unsigned short* __restrict__ H1b, int K1)
{
  __shared__ float red[4][128];
  if ((int)blockIdx.x < M0) spmv_body(A0, X0, H0, H0b, blockIdx.x, K0, red);
  else                      spmv_body(A1, X1, H1, H1b, blockIdx.x - M0, K1, red);
}

// ---------------------------------------------------------------------------
// Fused gh-GEMM + GRU (32-row tile; reads bf16 H)
// ---------------------------------------------------------------------------
DEV_INLINE void ghgru_body(
    const unsigned short* __restrict__ Hb, const unsigned short* __restrict__ Whhb,
    const float* __restrict__ bhh, const float* __restrict__ gi,
    const float* __restrict__ hv, float* __restrict__ out,
    unsigned short* __restrict__ outb, int M, int bm, unsigned short* As)
{
  const int tid = threadIdx.x;
#pragma unroll
  for (int i = 0; i < 2; ++i) {
    int s = tid + 256 * i;
    int row = s >> 4, c16 = s & 15;
    uint4 v = make_uint4(0, 0, 0, 0);
    int gr = bm + row;
    if (gr < M) v = *reinterpret_cast<const uint4*>(Hb + (size_t)gr * 128 + c16 * 8);
    *reinterpret_cast<uint4*>(&As[(row * 16 + (c16 ^ (row & 7))) * 8]) = v;
  }
  __syncthreads();

  const int wave = tid >> 6, lane = tid & 63;
  const int l31 = lane & 31, lhi = lane >> 5;
  const int d = wave * 32 + l31;

  f32x16 ar, az, an;
#pragma unroll
  for (int i = 0; i < 16; ++i) { ar[i] = 0.f; az[i] = 0.f; an[i] = 0.f; }

#pragma unroll
  for (int ks = 0; ks < 8; ++ks) {
    int c16 = ks * 2 + lhi;
    bf16x8 a = *reinterpret_cast<const bf16x8*>(&As[(l31 * 16 + (c16 ^ (l31 & 7))) * 8]);
    const unsigned short* wb = Whhb + (size_t)c16 * 8;
    bf16x8 br = *reinterpret_cast<const bf16x8*>(wb + (size_t)d * 128);
    bf16x8 bz = *reinterpret_cast<const bf16x8*>(wb + (size_t)(128 + d) * 128);
    bf16x8 bn = *reinterpret_cast<const bf16x8*>(wb + (size_t)(256 + d) * 128);
    ar = __builtin_amdgcn_mfma_f32_32x32x16_bf16(a, br, ar, 0, 0, 0);
    az = __builtin_amdgcn_mfma_f32_32x32x16_bf16(a, bz, az, 0, 0, 0);
    an = __builtin_amdgcn_mfma_f32_32x32x16_bf16(a, bn, an, 0, 0, 0);
  }

  const float b_r = bhh[d], b_z = bhh[128 + d], b_n = bhh[256 + d];
#pragma unroll
  for (int reg = 0; reg < 16; ++reg) {
    int r = bm + (reg & 3) + 8 * (reg >> 2) + 4 * lhi;
    if (r < M) {
      const float* gir = gi + (size_t)r * 384;
      float rr = 1.f / (1.f + __expf(-(gir[d] + ar[reg] + b_r)));
      float zz = 1.f / (1.f + __expf(-(gir[128 + d] + az[reg] + b_z)));
      float nn = tanhf(gir[256 + d] + rr * (an[reg] + b_n));
      float h = hv[(size_t)r * 128 + d];
      float o = (1.f - zz) * nn + zz * h;
      out[(size_t)r * 128 + d] = o;
      outb[(size_t)r * 128 + d] = f2bf(o);
    }
  }
}

__global__ __launch_bounds__(256) void gh_gru(
    const unsigned short* __restrict__ Hb, const unsigned short* __restrict__ Whhb,
    const float* __restrict__ bhh, const float* __restrict__ gi,
    const float* __restrict__ hv, float* __restrict__ out,
    unsigned short* __restrict__ outb, int M)
{
  __shared__ __align__(16) unsigned short As[32 * 128];
  ghgru_body(Hb, Whhb, bhh, gi, hv, out, outb, M, blockIdx.x * 32, As);
}

__global__ __launch_bounds__(256) void gh_gru2(
    const unsigned short* Hb0, const unsigned short* Whh0, const float* bhh0,
    const float* gi0, const float* hv0, float* out0, unsigned short* outb0,
    int M0, int nblk0,
    const unsigned short* Hb1, const unsigned short* Whh1, const float* bhh1,
    const float* gi1, const float* hv1, float* out1, unsigned short* outb1, int M1)
{
  __shared__ __align__(16) unsigned short As[32 * 128];
  if ((int)blockIdx.x < nblk0)
    ghgru_body(Hb0, Whh0, bhh0, gi0, hv0, out0, outb0, M0, blockIdx.x * 32, As);
  else
    ghgru_body(Hb1, Whh1, bhh1, gi1, hv1, out1, outb1, M1, (blockIdx.x - nblk0) * 32, As);
}

// ---------------------------------------------------------------------------
// Wave-per-row softmax / CE / tcp. f32-logits variant (stages 0+2).
// ---------------------------------------------------------------------------
DEV_INLINE void rowops_body(int lane, const float4* __restrict__ lr,
                            const float4* __restrict__ cr,
                            const float* __restrict__ srcrow,
                            float* __restrict__ scaledrow, float* __restrict__ cep)
{
  float4 e[6];
  float m = -3.4e38f;
#pragma unroll
  for (int k = 0; k < 6; ++k) {
    int idx = k * 64 + lane;
    if (idx < 375) {
      e[k] = lr[idx];
      m = fmaxf(m, fmaxf(fmaxf(e[k].x, e[k].y), fmaxf(e[k].z, e[k].w)));
    } else {
      e[k] = make_float4(-3.4e38f, -3.4e38f, -3.4e38f, -3.4e38f);
    }
  }
#pragma unroll
  for (int o = 1; o < 64; o <<= 1) m = fmaxf(m, __shfl_xor(m, o));
  float z = 0.f;
#pragma unroll
  for (int k = 0; k < 6; ++k) {
    e[k].x = __expf(e[k].x - m); e[k].y = __expf(e[k].y - m);
    e[k].z = __expf(e[k].z - m); e[k].w = __expf(e[k].w - m);
    z += (e[k].x + e[k].y) + (e[k].z + e[k].w);
  }
#pragma unroll
  for (int o = 1; o < 64; o <<= 1) z += __shfl_xor(z, o);
  float invZ1 = 1.0f / z;
  float m2 = invZ1;
  float t = 0.f, ls = 0.f, z2 = 0.f;
#pragma unroll
  for (int k = 0; k < 6; ++k) {
    int idx = k * 64 + lane;
    if (idx < 375) {
      float4 c = cr[idx];
      float px = e[k].x * invZ1, py = e[k].y * invZ1;
      float pz = e[k].z * invZ1, pw = e[k].w * invZ1;
      t  += c.x * px + c.y * py + c.z * pz + c.w * pw;
      ls += (c.x + c.y) + (c.z + c.w);
      z2 += __expf(px - m2) + __expf(py - m2) + __expf(pz - m2) + __expf(pw - m2);
    }
  }
#pragma unroll
  for (int o = 1; o < 64; o <<= 1) {
    t += __shfl_xor(t, o); ls += __shfl_xor(ls, o); z2 += __shfl_xor(z2, o);
  }
  if (lane == 0) *cep = t - ls * (m2 + logf(z2));
  scaledrow[lane]      = t * srcrow[lane];
  scaledrow[lane + 64] = t * srcrow[lane + 64];
}

__global__ __launch_bounds__(256) void rowops2(
    const float* lgA, const float* clsA_, const float* srcA, float* scA, float* ceA, int nA,
    const float* lgB, const float* clsB_, const float* srcB, float* scB, float* ceB, int nB)
{
  int gw = (blockIdx.x * 256 + threadIdx.x) >> 6;
  if (gw >= nA + nB) return;
  int lane = threadIdx.x & 63;
  if (gw < nA) {
    rowops_body(lane,
                reinterpret_cast<const float4*>(lgA + (size_t)gw * 1500),
                reinterpret_cast<const float4*>(clsA_ + (size_t)gw * 1500),
                srcA + (size_t)gw * 128, scA + (size_t)gw * 128, ceA + gw);
  } else {
    int r = gw - nA;
    rowops_body(lane,
                reinterpret_cast<const float4*>(lgB + (size_t)r * 1500),
                reinterpret_cast<const float4*>(clsB_ + (size_t)r * 1500),
                srcB + (size_t)r * 128, scB + (size_t)r * 128, ceB + r);
  }
}

// bf16-logits variant (stages 1/3/4): logits row = 750 uints (bf16 pairs)
DEV_INLINE void rowops_body_b(int lane, const unsigned* __restrict__ lrb,
                              const float2* __restrict__ cr2,
                              const float* __restrict__ srcrow,
                              float* __restrict__ scaledrow, float* __restrict__ cep)
{
  float2 e[12];
  float m = -3.4e38f;
#pragma unroll
  for (int k = 0; k < 12; ++k) {
    int idx = k * 64 + lane;
    if (idx < 750) {
      e[k] = bfpair(lrb[idx]);
      m = fmaxf(m, fmaxf(e[k].x, e[k].y));
    } else {
      e[k] = make_float2(-3.4e38f, -3.4e38f);
    }
  }
#pragma unroll
  for (int o = 1; o < 64; o <<= 1) m = fmaxf(m, __shfl_xor(m, o));
  float z = 0.f;
#pragma unroll
  for (int k = 0; k < 12; ++k) {
    e[k].x = __expf(e[k].x - m); e[k].y = __expf(e[k].y - m);
    z += e[k].x + e[k].y;
  }
#pragma unroll
  for (int o = 1; o < 64; o <<= 1) z += __shfl_xor(z, o);
  float invZ1 = 1.0f / z;
  float m2 = invZ1;
  float t = 0.f, ls = 0.f, z2 = 0.f;
#pragma unroll
  for (int k = 0; k < 12; ++k) {
    int idx = k * 64 + lane;
    if (idx < 750) {
      float2 c = cr2[idx];
      float px = e[k].x * invZ1, py = e[k].y * invZ1;
      t  += c.x * px + c.y * py;
      ls += c.x + c.y;
      z2 += __expf(px - m2) + __expf(py - m2);
    }
  }
#pragma unroll
  for (int o = 1; o < 64; o <<= 1) {
    t += __shfl_xor(t, o); ls += __shfl_xor(ls, o); z2 += __shfl_xor(z2, o);
  }
  if (lane == 0) *cep = t - ls * (m2 + logf(z2));
  scaledrow[lane]      = t * srcrow[lane];
  scaledrow[lane + 64] = t * srcrow[lane + 64];
}

__global__ __launch_bounds__(256) void rowops2b(
    const unsigned* lgA, const float* clsA_, const float* srcA, float* scA, float* ceA, int nA,
    const unsigned* lgB, const float* clsB_, const float* srcB, float* scB, float* ceB, int nB)
{
  int gw = (blockIdx.x * 256 + threadIdx.x) >> 6;
  if (gw >= nA + nB) return;
  int lane = threadIdx.x & 63;
  if (gw < nA) {
    rowops_body_b(lane, lgA + (size_t)gw * 750,
                  reinterpret_cast<const float2*>(clsA_ + (size_t)gw * 1500),
                  srcA + (size_t)gw * 128, scA + (size_t)gw * 128, ceA + gw);
  } else {
    int r = gw - nA;
    rowops_body_b(lane, lgB + (size_t)r * 750,
                  reinterpret_cast<const float2*>(clsB_ + (size_t)r * 1500),
                  srcB + (size_t)r * 128, scB + (size_t)r * 128, ceB + r);
  }
}

__global__ __launch_bounds__(256) void rowops1b(
    const unsigned* lg, const float* cls, const float* src, float* sc, float* ce, int n)
{
  int gw = (blockIdx.x * 256 + threadIdx.x) >> 6;
  if (gw >= n) return;
  int lane = threadIdx.x & 63;
  rowops_body_b(lane, lg + (size_t)gw * 750,
                reinterpret_cast<const float2*>(cls + (size_t)gw * 1500),
                src + (size_t)gw * 128, sc + (size_t)gw * 128, ce + gw);
}

// ---------------------------------------------------------------------------
// Fuse pipeline
// ---------------------------------------------------------------------------
__global__ __launch_bounds__(256) void fuse_scores_all(
    const float* __restrict__ e0, const float* __restrict__ e1,
    const float* __restrict__ W2, const float* __restrict__ b2,
    const float* __restrict__ W3, const float* __restrict__ b3,
    float* __restrict__ s0, float* __restrict__ s1)
{
  int lane = threadIdx.x & 63;
  int row = (blockIdx.x * 256 + threadIdx.x) >> 6;
  if (row >= 18500) return;
  float a0 = e0[(size_t)row * 128 + lane] * W2[lane] + e0[(size_t)row * 128 + 64 + lane] * W2[64 + lane];
  float a1 = e1[(size_t)row * 128 + lane] * W3[lane] + e1[(size_t)row * 128 + 64 + lane] * W3[64 + lane];
#pragma unroll
  for (int o = 32; o > 0; o >>= 1) { a0 += __shfl_down(a0, o); a1 += __shfl_down(a1, o); }
  if (lane == 0) {
    s0[row] = fmaxf(a0 + b2[0], 0.f);
    s1[row] = fmaxf(a1 + b3[0], 0.f);
  }
}

__global__ __launch_bounds__(1024) void denom4(
    const float* __restrict__ s0, const float* __restrict__ s1,
    float* __restrict__ den)
{
  __shared__ float red[1024];
  const int ns[4]   = {8000, 3000, 1500, 6000};
  const int offs[4] = {0, 8000, 11000, 12500};
  int b = blockIdx.x;
  int n = ns[b];
  const float* p0 = s0 + offs[b];
  const float* p1 = s1 + offs[b];
  int tid = threadIdx.x;
  float m = -3.4e38f;
  for (int i = tid; i < n; i += 1024) m = fmaxf(m, p0[i]);
  red[tid] = m; __syncthreads();
  for (int s = 512; s > 0; s >>= 1) { if (tid < s) red[tid] = fmaxf(red[tid], red[tid + s]); __syncthreads(); }
  float m0 = red[0]; __syncthreads();
  float z = 0.f;
  for (int i = tid; i < n; i += 1024) z += __expf(p0[i] - m0);
  red[tid] = z; __syncthreads();
  for (int s = 512; s > 0; s >>= 1) { if (tid < s) red[tid] += red[tid + s]; __syncthreads(); }
  float Z0 = red[0]; __syncthreads();
  m = -3.4e38f;
  for (int i = tid; i < n; i += 1024) m = fmaxf(m, p1[i]);
  red[tid] = m; __syncthreads();
  for (int s = 512; s > 0; s >>= 1) { if (tid < s) red[tid] = fmaxf(red[tid], red[tid + s]); __syncthreads(); }
  float m1 = red[0]; __syncthreads();
  z = 0.f;
  for (int i = tid; i < n; i += 1024) z += __expf(p1[i] - m1);
  red[tid] = z; __syncthreads();
  for (int s = 512; s > 0; s >>= 1) { if (tid < s) red[tid] += red[tid + s]; __syncthreads(); }
  if (tid == 0) { den[b * 4] = m0; den[b * 4 + 1] = Z0; den[b * 4 + 2] = m1; den[b * 4 + 3] = red[0]; }
}

__global__ __launch_bounds__(256) void fuse_emb_all(
    const float* __restrict__ e0, const float* __restrict__ e1,
    const float* __restrict__ s0, const float* __restrict__ s1,
    const float* __restrict__ den, const float* __restrict__ rel,
    float* __restrict__ fe, unsigned short* __restrict__ feb,
    float* __restrict__ rel_out)
{
  int t = blockIdx.x * 256 + threadIdx.x;
  const int tot2 = 18500 * 64;
  if (t < tot2) {
    int idx = t * 2;
    int row = idx >> 7;
    int e = (row < 8000) ? 0 : (row < 11000) ? 1 : (row < 12500) ? 2 : 3;
    float a0 = __expf(s0[row] - den[e * 4]) / den[e * 4 + 1];
    float a1 = __expf(s1[row] - den[e * 4 + 2]) / den[e * 4 + 3];
    float2 v0 = *reinterpret_cast<const float2*>(e0 + idx);
    float2 v1 = *reinterpret_cast<const float2*>(e1 + idx);
    float r0 = fmaxf(a0 * v0.x + a1 * v1.x, 0.f);
    float r1 = fmaxf(a0 * v0.y + a1 * v1.y, 0.f);
    *reinterpret_cast<float2*>(fe + idx) = make_float2(r0, r1);
    unsigned pb = (unsigned)f2bf(r0) | ((unsigned)f2bf(r1) << 16);
    *reinterpret_cast<unsigned*>(feb + idx) = pb;
  } else if (t < tot2 + 768) {
    int k = (t - tot2) * 2;
    *reinterpret_cast<float2*>(rel_out + k) = *reinterpret_cast<const float2*>(rel + k);
  }
}

// ---------------------------------------------------------------------------
// Edge losses: half-wave (32 lanes) per edge, fast tanh, index prefetch.
// Blocks [0,1024) -> u_d, [1024,2048) -> u_s.
// ---------------------------------------------------------------------------
__global__ __launch_bounds__(256) void edge_both(
    const int* __restrict__ ud, const int* __restrict__ us,
    const unsigned short* __restrict__ feb, const unsigned short* __restrict__ relb,
    float* __restrict__ partial, int En)
{
  const int tid = threadIdx.x;
  const int lane = tid & 63;
  const int l = lane & 31, h = lane >> 5;
  const int wid = tid >> 6;
  bool is_d = (blockIdx.x < 1024);
  int bb = is_d ? blockIdx.x : blockIdx.x - 1024;
  int e = (bb * 4 + wid) * 2 + h;
  const int ns = 1024 * 4 * 2;
  float acc = 0.f;
  if (is_d) {
    int4 ei = (e < En) ? *reinterpret_cast<const int4*>(ud + (size_t)e * 4)
                       : make_int4(0, 0, 0, 0);
    for (; e < En; e += ns) {
      int en = e + ns;
      int4 ein = (en < En) ? *reinterpret_cast<const int4*>(ud + (size_t)en * 4)
                           : make_int4(0, 0, 0, 0);
      uint2 a = reinterpret_cast<const uint2*>(feb + (size_t)ei.x * 128)[l];
      uint2 b = reinterpret_cast<const uint2*>(feb + (size_t)ei.y * 128)[l];
      uint2 r = reinterpret_cast<const uint2*>(relb + (size_t)ei.w * 128)[l];
      float2 a0 = bfpair(a.x), a1 = bfpair(a.y);
      float2 b0 = bfpair(b.x), b1 = bfpair(b.y);
      float2 r0 = bfpair(r.x), r1 = bfpair(r.y);
      float d = r0.x * ftanh(a0.x + b0.x) + r0.y * ftanh(a0.y + b0.y)
              + r1.x * ftanh(a1.x + b1.x) + r1.y * ftanh(a1.y + b1.y);
#pragma unroll
      for (int o = 1; o < 32; o <<= 1) d += __shfl_xor(d, o);
      if (l == 0) acc += softplus_neg((float)ei.z * d);
      ei = ein;
    }
  } else {
    int3 ei = make_int3(0, 0, 0);
    if (e < En) { ei.x = us[(size_t)e * 3]; ei.y = us[(size_t)e * 3 + 1]; ei.z = us[(size_t)e * 3 + 2]; }
    for (; e < En; e += ns) {
      int en = e + ns;
      int3 ein = make_int3(0, 0, 0);
      if (en < En) { ein.x = us[(size_t)en * 3]; ein.y = us[(size_t)en * 3 + 1]; ein.z = us[(size_t)en * 3 + 2]; }
      uint2 a = reinterpret_cast<const uint2*>(feb + (size_t)ei.x * 128)[l];
      uint2 b = reinterpret_cast<const uint2*>(feb + (size_t)ei.y * 128)[l];
      float2 a0 = bfpair(a.x), a1 = bfpair(a.y);
      float2 b0 = bfpair(b.x), b1 = bfpair(b.y);
      float d = a0.x * b0.x + a0.y * b0.y + a1.x * b1.x + a1.y * b1.y;
#pragma unroll
      for (int o = 1; o < 32; o <<= 1) d += __shfl_xor(d, o);
      if (l == 0) acc += softplus_neg((float)ei.z * d);
      ei = ein;
    }
  }
  __shared__ float red[8];
  if (l == 0) red[wid * 2 + h] = acc;
  __syncthreads();
  if (tid == 0) {
    float s = 0.f;
#pragma unroll
    for (int i = 0; i < 8; ++i) s += red[i];
    partial[blockIdx.x] = s;
  }
}

__global__ __launch_bounds__(1024) void final_reduce(
    const float* __restrict__ partial, const float* __restrict__ cebuf,
    float* __restrict__ out)
{
  __shared__ float red[1024];
  __shared__ float total;
  int tid = threadIdx.x;
  if (tid == 0) total = 0.f;
  __syncthreads();
  float a = partial[tid] + partial[tid + 1024];
  red[tid] = a; __syncthreads();
  for (int s = 512; s > 0; s >>= 1) { if (tid < s) red[tid] += red[tid + s]; __syncthreads(); }
  if (tid == 0) total += red[0];
  __syncthreads();
  const int ns[5] = {3000, 8000, 6000, 8000, 3000};
#pragma unroll
  for (int seg = 0; seg < 5; ++seg) {
    const float* v = cebuf + seg * 8000;
    float s = 0.f;
    for (int i = tid; i < ns[seg]; i += 1024) s += v[i];
    red[tid] = s; __syncthreads();
    for (int st = 512; st > 0; st >>= 1) { if (tid < st) red[tid] += red[tid + st]; __syncthreads(); }
    if (tid == 0) total -= red[0] / (float)ns[seg];
    __syncthreads();
  }
  if (tid == 0) out[0] = total;
}

// ---------------------------------------------------------------------------
extern "C" void kernel_launch(void* const* d_in, const int* in_sizes, int n_in,
                              void* d_out, int out_size, void* d_ws, size_t ws_size,
                              hipStream_t stream)
{
  const float* feat_P = (const float*)d_in[0];
  const float* feat_V = (const float*)d_in[1];
  const float* feat_C = (const float*)d_in[2];
  const float* feat_A = (const float*)d_in[3];
  const float* W1 = (const float*)d_in[4];
  const float* b1 = (const float*)d_in[5];
  const float* W2 = (const float*)d_in[6];
  const float* b2 = (const float*)d_in[7];
  const float* W3 = (const float*)d_in[8];
  const float* b3 = (const float*)d_in[9];
  const float* L00W = (const float*)d_in[10];
  const float* L00b = (const float*)d_in[11];
  const float* L01W = (const float*)d_in[12];
  const float* L01b = (const float*)d_in[13];
  const float* L10W = (const float*)d_in[14];
  const float* L10b = (const float*)d_in[15];
  const float* L11W = (const float*)d_in[16];
  const float* L11b = (const float*)d_in[17];
  const float* L12W = (const float*)d_in[18];
  const float* L12b = (const float*)d_in[19];
  const float* g0_Wih = (const float*)d_in[20];
  const float* g0_Whh = (const float*)d_in[21];
  const float* g0_bih = (const float*)d_in[22];
  const float* g0_bhh = (const float*)d_in[23];
  const float* g1_Wih = (const float*)d_in[24];
  const float* g1_Whh = (const float*)d_in[25];
  const float* g1_bih = (const float*)d_in[26];
  const float* g1_bhh = (const float*)d_in[27];
  const float* rel_emb = (const float*)d_in[28];
  const float* adj00 = (const float*)d_in[29];
  const float* adj01 = (const float*)d_in[30];
  const float* adj10 = (const float*)d_in[31];
  const float* adj11 = (const float*)d_in[32];
  const float* adj12 = (const float*)d_in[33];
  const float* clsA = (const float*)d_in[34];
  const float* clsP = (const float*)d_in[35];
  const float* clsV = (const float*)d_in[36];
  const int* u_s = (const int*)d_in[37];
  const int* u_d = (const int*)d_in[38];

  float* out = (float*)d_out;
  float* fe = out + 1;
  float* rel_out = out + 1 + 18500 * 128;

  float* ws = (float*)d_ws;
  size_t o = 0;
  auto alloc = [&](size_t n) { float* p = ws + o; o += n; return p; };
  float* selfb   = alloc((size_t)18500 * 128);
  float* stcat   = alloc((size_t)18500 * 128);   // P0|V1|C1|A0
  float* stP1    = alloc((size_t)8000 * 128);
  float* gi      = alloc((size_t)26500 * 384);
  float* logits0 = alloc((size_t)3000 * 1500);   // stage 0 (f32)
  float* logits2 = alloc((size_t)6000 * 1500);   // stage 2 (f32)
  float* scaled0 = alloc((size_t)3000 * 128);
  float* scaled1 = alloc((size_t)8000 * 128);
  float* scaled2 = alloc((size_t)6000 * 128);
  float* scaled3 = alloc((size_t)8000 * 128);
  float* scaled4 = alloc((size_t)3000 * 128);
  float* h0      = alloc((size_t)8000 * 128);
  float* h2      = alloc((size_t)8000 * 128);
  float* h1      = alloc((size_t)6000 * 128);
  float* h3      = alloc((size_t)3000 * 128);
  float* h4      = alloc((size_t)1500 * 128);
  float* cebuf   = alloc(5 * 8000);
  float* s0b = alloc(18500);
  float* s1b = alloc(18500);
  float* den = alloc(16);
  float* partial = alloc(2048);
  auto allocb = [&](size_t nelem) { unsigned short* p = (unsigned short*)(ws + o); o += (nelem + 1) / 2; return p; };
  unsigned short* featb  = allocb((size_t)18500 * 128);
  unsigned short* stcatb = allocb((size_t)18500 * 128);
  unsigned short* stP1b  = allocb((size_t)8000 * 128);
  unsigned short* feb    = allocb((size_t)18500 * 128);
  unsigned short* h0b    = allocb((size_t)8000 * 128);
  unsigned short* h2b    = allocb((size_t)8000 * 128);
  unsigned short* h1b    = allocb((size_t)6000 * 128);
  unsigned short* h3b    = allocb((size_t)3000 * 128);
  unsigned short* h4b    = allocb((size_t)1500 * 128);
  unsigned short* lg1b   = allocb((size_t)8000 * 1500);  // bf16 logits stage 1 (and 4)
  unsigned short* lg3b   = allocb((size_t)8000 * 1500);  // bf16 logits stage 3
  unsigned short* relb   = allocb(12 * 128);
  unsigned short* W1b = allocb(128 * 128);
  unsigned short* L00Wb = allocb(1500 * 128);
  unsigned short* L01Wb = allocb(1500 * 128);
  unsigned short* L10Wb = allocb(1500 * 128);
  unsigned short* L11Wb = allocb(1500 * 128);
  unsigned short* L12Wb = allocb(1500 * 128);
  unsigned short* g0Wihb = allocb(384 * 128);
  unsigned short* g0Whhb = allocb(384 * 128);
  unsigned short* g1Wihb = allocb(384 * 128);
  unsigned short* g1Whhb = allocb(384 * 128);
  unsigned short* featPb = featb;
  unsigned short* featVb = featb + (size_t)8000 * 128;
  unsigned short* featCb = featb + (size_t)11000 * 128;
  unsigned short* featAb = featb + (size_t)12500 * 128;
  float* stP0 = stcat;
  float* stV1 = stcat + (size_t)8000 * 128;
  float* stC1 = stcat + (size_t)11000 * 128;
  float* stA0 = stcat + (size_t)12500 * 128;
  unsigned short* stP0b = stcatb;
  unsigned short* stV1b = stcatb + (size_t)8000 * 128;
  unsigned short* stC1b = stcatb + (size_t)11000 * 128;
  unsigned short* stA0b = stcatb + (size_t)12500 * 128;
  (void)ws_size; (void)in_sizes; (void)n_in; (void)out_size;

  dim3 blk(256);

  // --- 1. batched f32->bf16 conversion ---
  CvtArgs ca{};
  int nseg = 0, totblk = 0;
  auto addseg = [&](const float* src, unsigned short* dst, int n) {
    ca.seg[nseg].src = src; ca.seg[nseg].dst = dst; ca.seg[nseg].n = n;
    ca.seg[nseg].nblk = (n + 1023) / 1024; totblk += ca.seg[nseg].nblk; ++nseg;
  };
  addseg(feat_P, featPb, 8000 * 128);
  addseg(feat_V, featVb, 3000 * 128);
  addseg(feat_C, featCb, 1500 * 128);
  addseg(feat_A, featAb, 6000 * 128);
  addseg(W1, W1b, 128 * 128);
  addseg(L00W, L00Wb, 1500 * 128);
  addseg(L01W, L01Wb, 1500 * 128);
  addseg(L10W, L10Wb, 1500 * 128);
  addseg(L11W, L11Wb, 1500 * 128);
  addseg(L12W, L12Wb, 1500 * 128);
  addseg(g0_Wih, g0Wihb, 384 * 128);
  addseg(g0_Whh, g0Whhb, 384 * 128);
  addseg(g1_Wih, g1Wihb, 384 * 128);
  addseg(g1_Whh, g1Whhb, 384 * 128);
  addseg(rel_emb, relb, 12 * 128);
  ca.nseg = nseg;
  hipLaunchKernelGGL(convert_bf16_many, dim3(totblk), blk, 0, stream, ca);

  const size_t giOff[5] = {0, 8000, 14000, 22000, 25000};

  // --- 2. static GEMMs (self + 5 gi + f32 logits for stages 0,2) ---
  {
    GSegs gs{};
    int nb = 0, k = 0;
    auto add = [&](const unsigned short* X, const unsigned short* W, const float* bias,
                   float* C, int N, int O) {
      int xb = (N + 127) / 128, yb = (O + 63) / 64;
      gs.s[k] = GSeg{X, W, bias, C, N, O, nb, xb};
      nb += xb * yb; ++k;
    };
    add(featb,  W1b,    b1,     selfb,               18500, 128);
    add(featPb, g0Wihb, g0_bih, gi + giOff[0] * 384, 8000, 384);
    add(featAb, g0Wihb, g0_bih, gi + giOff[1] * 384, 6000, 384);
    add(featPb, g1Wihb, g1_bih, gi + giOff[2] * 384, 8000, 384);
    add(featVb, g1Wihb, g1_bih, gi + giOff[3] * 384, 3000, 384);
    add(featCb, g1Wihb, g1_bih, gi + giOff[4] * 384, 1500, 384);
    add(featVb, L00Wb,  L00b,   logits0,             3000, 1500);
    add(featAb, L10Wb,  L10b,   logits2,             6000, 1500);
    gs.nseg = k;
    hipLaunchKernelGGL(gemm_bf16_gseg, dim3(nb), blk, 0, stream, gs);
  }

  // --- 3. rowops stages 0+2 (f32 logits) ---
  hipLaunchKernelGGL(rowops2, dim3((9000 * 64 + 255) / 256), blk, 0, stream,
                     logits0, clsV, feat_V, scaled0, cebuf + 0 * 8000, 3000,
                     logits2, clsA, feat_A, scaled2, cebuf + 2 * 8000, 6000);
  // --- 4. spmv stages 0+2 ---
  hipLaunchKernelGGL(spmv_scan2, dim3(16000), blk, 0, stream,
                     adj00, scaled0, h0, h0b, 8000, 3000,
                     adj10, scaled2, h2, h2b, 6000);
  // --- 5. gh_gru stages 0+2 -> stP0, stP1 ---
  hipLaunchKernelGGL(gh_gru2, dim3(500), blk, 0, stream,
                     h0b, g0Whhb, g0_bhh, gi + giOff[0] * 384, h0, stP0, stP0b, 8000, 250,
                     h2b, g1Whhb, g1_bhh, gi + giOff[2] * 384, h2, stP1, stP1b, 8000);
  // --- 6. logits stages 1+3 (bf16 out) ---
  {
    GBSegs gs{};
    gs.s[0] = GBSeg{stP0b, L01Wb, L01b, lg1b, 8000, 1500, 0,    63};
    gs.s[1] = GBSeg{stP1b, L11Wb, L11b, lg3b, 8000, 1500, 1512, 63};
    gs.nseg = 2;
    hipLaunchKernelGGL(gemm_bf16o_gseg, dim3(3024), blk, 0, stream, gs);
  }
  // --- 7. rowops stages 1+3 (bf16 logits) ---
  hipLaunchKernelGGL(rowops2b, dim3((16000 * 64 + 255) / 256), blk, 0, stream,
                     (const unsigned*)lg1b, clsP, stP0, scaled1, cebuf + 1 * 8000, 8000,
                     (const unsigned*)lg3b, clsP, stP1, scaled3, cebuf + 3 * 8000, 8000);
  // --- 8. spmv stages 1+3 ---
  hipLaunchKernelGGL(spmv_scan2, dim3(9000), blk, 0, stream,
                     adj01, scaled1, h1, h1b, 6000, 8000,
                     adj11, scaled3, h3, h3b, 8000);
  // --- 9. gh_gru stages 1+3 -> stA0, stV1 ---
  hipLaunchKernelGGL(gh_gru2, dim3(188 + 94), blk, 0, stream,
                     h1b, g0Whhb, g0_bhh, gi + giOff[1] * 384, h1, stA0, stA0b, 6000, 188,
                     h3b, g1Whhb, g1_bhh, gi + giOff[3] * 384, h3, stV1, stV1b, 3000);
  // --- 10-13. stage 4 ---
  {
    GBSegs gs{};
    gs.s[0] = GBSeg{stV1b, L12Wb, L12b, lg1b, 3000, 1500, 0, 24};
    gs.nseg = 1;
    hipLaunchKernelGGL(gemm_bf16o_gseg, dim3(24 * 24), blk, 0, stream, gs);
  }
  hipLaunchKernelGGL(rowops1b, dim3((3000 * 64 + 255) / 256), blk, 0, stream,
                     (const unsigned*)lg1b, clsV, stV1, scaled4, cebuf + 4 * 8000, 3000);
  hipLaunchKernelGGL(spmv_scan, dim3(1500), blk, 0, stream, adj12, scaled4, h4, h4b, 1500, 3000);
  hipLaunchKernelGGL(gh_gru, dim3(47), blk, 0, stream,
                     h4b, g1Whhb, g1_bhh, gi + giOff[4] * 384, h4, stC1, stC1b, 1500);

  // --- 14-16. fuse pipeline ---
  hipLaunchKernelGGL(fuse_scores_all, dim3((18500 + 3) / 4), blk, 0, stream,
                     selfb, stcat, W2, b2, W3, b3, s0b, s1b);
  hipLaunchKernelGGL(denom4, dim3(4), dim3(1024), 0, stream, s0b, s1b, den);
  hipLaunchKernelGGL(fuse_emb_all, dim3((18500 * 64 + 768 + 255) / 256), blk, 0, stream,
                     selfb, stcat, s0b, s1b, den, rel_emb, fe, feb, rel_out);

  // --- 17. edges ---
  hipLaunchKernelGGL(edge_both, dim3(2048), blk, 0, stream, u_d, u_s, feb, relb, partial, 150000);

  // --- 18. final ---
  hipLaunchKernelGGL(final_reduce, dim3(1), dim3(1024), 0, stream, partial, cebuf, out);
}